// Round 8
// baseline (2404.892 us; speedup 1.0000x reference)
//
#include <hip/hip_runtime.h>
#include <stdint.h>

typedef __attribute__((ext_vector_type(8))) short bf16x8;
typedef __attribute__((ext_vector_type(4))) short bf16x4;
typedef __attribute__((ext_vector_type(4))) float fx4;
typedef __attribute__((ext_vector_type(4))) unsigned short ushx4;
typedef unsigned short ush;

#define DEV __device__ __forceinline__

DEV unsigned short f2bf(float f) {
  unsigned u = __float_as_uint(f);
  u += 0x7fffu + ((u >> 16) & 1u);
  return (unsigned short)(u >> 16);
}

DEV float bf2f(ush u) { return __uint_as_float(((unsigned)u) << 16); }

DEV float fast_exp2(float x) { return __builtin_amdgcn_exp2f(x); }

// packed f32x2 -> bf16x2 (RNE), single VALU op
DEV unsigned pk_bf16(float a, float b) {
  unsigned r;
  asm("v_cvt_pk_bf16_f32 %0, %1, %2" : "=v"(r) : "v"(a), "v"(b));
  return r;
}

DEV void async16(const void* g, void* l) {
  __builtin_amdgcn_global_load_lds(
      (const __attribute__((address_space(1))) unsigned*)g,
      (__attribute__((address_space(3))) unsigned*)l, 16, 0, 0);
}

// softmax scale folded into Q: 1/sqrt(64) * log2(e)
#define QSCALE 0.18033688011112042f

// ---------------- weight prep: fp32 (K,N) -> bf16 (N,K) transposed ----------
#define WSTRIDE 3145728

__global__ __launch_bounds__(256) void k_prep_weights(
    const float* __restrict__ Wq, const float* __restrict__ Wk,
    const float* __restrict__ Wv, const float* __restrict__ Wo,
    const float* __restrict__ W1, const float* __restrict__ W2,
    ush* __restrict__ wbf) {
  __shared__ float tile[32][33];
  int bid = blockIdx.x;
  int l = bid / 3072, r = bid % 3072;
  const float* src; ush* dst; int R, Cc, t;
  if (r < 768) {
    int w = r >> 8; t = r & 255; R = 512; Cc = 512;
    src = (w == 0 ? Wq : (w == 1 ? Wk : Wv)) + (size_t)l * 262144;
    dst = wbf + (size_t)l * WSTRIDE + w * 262144;
  } else if (r < 1024) {
    t = r - 768; R = 512; Cc = 512;
    src = Wo + (size_t)l * 262144; dst = wbf + (size_t)l * WSTRIDE + 786432;
  } else if (r < 2048) {
    t = r - 1024; R = 512; Cc = 2048;
    src = W1 + (size_t)l * 1048576; dst = wbf + (size_t)l * WSTRIDE + 1048576;
  } else {
    t = r - 2048; R = 2048; Cc = 512;
    src = W2 + (size_t)l * 1048576; dst = wbf + (size_t)l * WSTRIDE + 2097152;
  }
  int tpr = Cc >> 5;
  int trow = t / tpr, tcol = t % tpr;
  int tx = threadIdx.x & 31, ty = threadIdx.x >> 5;
#pragma unroll
  for (int i = 0; i < 4; i++) {
    int rr = trow * 32 + ty + i * 8, cc = tcol * 32 + tx;
    tile[ty + i * 8][tx] = src[(size_t)rr * Cc + cc];
  }
  __syncthreads();
#pragma unroll
  for (int i = 0; i < 4; i++) {
    int cc = tcol * 32 + ty + i * 8, rr = trow * 32 + tx;
    dst[(size_t)cc * R + rr] = f2bf(tile[tx][ty + i * 8]);
  }
}

__global__ __launch_bounds__(256) void k_pack_bias(
    const float* __restrict__ bq, const float* __restrict__ bk,
    const float* __restrict__ bv, float* __restrict__ dst) {
  int idx = blockIdx.x * 256 + threadIdx.x;
  if (idx >= 6 * 1536) return;
  int l = idx / 1536, r = idx % 1536;
  float v = (r < 512) ? bq[l * 512 + r]
            : (r < 1024) ? bk[l * 512 + r - 512] : bv[l * 512 + r - 1024];
  dst[idx] = v;
}

// ---------------- embed: (B,C,HW) transpose -> x (B,T,C) fp32 + pos ---------
__global__ __launch_bounds__(256) void k_embed(
    const float* __restrict__ img, const float* __restrict__ rad,
    const float* __restrict__ pos, float* __restrict__ x) {
  __shared__ float tile[32][33];
  int bid = blockIdx.x;
  int b = bid / 640, r2 = bid % 640;
  int tc = r2 / 40, tt = r2 % 40;
  int tx = threadIdx.x & 31, ty = threadIdx.x >> 5;
#pragma unroll
  for (int i = 0; i < 4; i++) {
    int c = tc * 32 + ty + i * 8, t = tt * 32 + tx;
    float v = (t < 1024) ? img[(size_t)(b * 512 + c) * 1024 + t]
                         : rad[(size_t)(b * 512 + c) * 256 + (t - 1024)];
    tile[ty + i * 8][tx] = v;
  }
  __syncthreads();
#pragma unroll
  for (int i = 0; i < 4; i++) {
    int t = tt * 32 + ty + i * 8, c = tc * 32 + tx;
    x[(size_t)(b * 1280 + t) * 512 + c] = tile[tx][ty + i * 8] + pos[(size_t)t * 512 + c];
  }
}

// ---------------- layernorm (fp32 in, bf16 out): one wave per row -----------
__global__ __launch_bounds__(256) void k_ln_bf16(
    const float* __restrict__ x, const float* __restrict__ w,
    const float* __restrict__ bia, ush* __restrict__ h) {
  int wave = threadIdx.x >> 6, lane = threadIdx.x & 63;
  int row = blockIdx.x * 4 + wave;
  int c0 = lane * 8;
  const float4* xr = (const float4*)(x + (size_t)row * 512 + c0);
  float4 a = xr[0], b4 = xr[1];
  float v[8] = {a.x, a.y, a.z, a.w, b4.x, b4.y, b4.z, b4.w};
  float s = 0.f, s2 = 0.f;
#pragma unroll
  for (int e = 0; e < 8; e++) { s += v[e]; s2 += v[e] * v[e]; }
#pragma unroll
  for (int mask = 1; mask < 64; mask <<= 1) {
    s += __shfl_xor(s, mask, 64);
    s2 += __shfl_xor(s2, mask, 64);
  }
  float mean = s * (1.f / 512.f);
  float var = s2 * (1.f / 512.f) - mean * mean;
  float rstd = rsqrtf(var + 1e-5f);
  bf16x8 o;
#pragma unroll
  for (int e = 0; e < 8; e++)
    o[e] = (short)f2bf((v[e] - mean) * rstd * w[c0 + e] + bia[c0 + e]);
  *(bf16x8*)(h + (size_t)row * 512 + c0) = o;
}

__global__ __launch_bounds__(256) void k_ln_final(
    const float* __restrict__ x, const float* __restrict__ w,
    const float* __restrict__ bia, float* __restrict__ out) {
  int wave = threadIdx.x >> 6, lane = threadIdx.x & 63;
  int row = blockIdx.x * 4 + wave;
  int c0 = lane * 8;
  const float4* xr = (const float4*)(x + (size_t)row * 512 + c0);
  float4 a = xr[0], b4 = xr[1];
  float v[8] = {a.x, a.y, a.z, a.w, b4.x, b4.y, b4.z, b4.w};
  float s = 0.f, s2 = 0.f;
#pragma unroll
  for (int e = 0; e < 8; e++) { s += v[e]; s2 += v[e] * v[e]; }
#pragma unroll
  for (int mask = 1; mask < 64; mask <<= 1) {
    s += __shfl_xor(s, mask, 64);
    s2 += __shfl_xor(s2, mask, 64);
  }
  float mean = s * (1.f / 512.f);
  float var = s2 * (1.f / 512.f) - mean * mean;
  float rstd = rsqrtf(var + 1e-5f);
  int b = row / 1280, t = row % 1280;
  size_t orow = (t < 1024) ? ((size_t)b * 1024 + t)
                           : (16384 + (size_t)b * 256 + (t - 1024));
  float o[8];
#pragma unroll
  for (int e = 0; e < 8; e++)
    o[e] = (v[e] - mean) * rstd * w[c0 + e] + bia[c0 + e];
  float4* op = (float4*)(out + orow * 512 + c0);
  op[0] = make_float4(o[0], o[1], o[2], o[3]);
  op[1] = make_float4(o[4], o[5], o[6], o[7]);
}

// ---------------- GEMM: A (M,K) bf16 row-major @ Wt (N,K) bf16 row-major ----
// XCD-swizzled grid; optional split-K (kzn>1, MODE 2 only): gridDim.y =
// (M/128)*kzn; each split handles K/kzn and atomicAdds into fp32 out.
// MODE 0: out bf16; MODE 1: bf16+ReLU; MODE 2: fp32 residual atomicAdd;
// MODE 3: QKV — col<512: Q pre-scaled; 512..1023: K; >=1024: V -> vt permuted
template <int MODE>
__global__ __launch_bounds__(256) void k_gemm(
    const ush* __restrict__ A, const ush* __restrict__ Wt,
    const float* __restrict__ bias, void* __restrict__ outv,
    ush* __restrict__ vt2, int M, int N, int K, int kzn) {
  __shared__ char smem[32768];
  char* As = smem;
  char* Bs = smem + 16384;
  const int tid = threadIdx.x;
  // XCD swizzle: id = y*gx+x; xcd = id&7; per-XCD: n-blocks contiguous
  int id = blockIdx.y * gridDim.x + blockIdx.x;
  int xcd = id & 7, s = id >> 3;
  int nb_n = gridDim.x;
  int strips_per_xcd = gridDim.y >> 3;
  int mcount = M >> 7;
  int mblk_full = xcd * strips_per_xcd + s / nb_n;
  int kz = mblk_full / mcount;          // 0..kzn-1
  int mblk = mblk_full - kz * mcount;
  int nblk = s % nb_n;
  const int m0 = mblk << 7, n0 = nblk << 7;
  const int kpc = K / kzn;
  const int kbeg = kz * kpc;
  const int lane = tid & 63, wave = tid >> 6;
  const int quad = lane >> 4, l16 = lane & 15;
  const int m_off = (wave & 1) << 6, n_off = (wave >> 1) << 6;
  fx4 acc[4][4];
#pragma unroll
  for (int a = 0; a < 4; a++)
#pragma unroll
    for (int b = 0; b < 4; b++) acc[a][b] = (fx4){0.f, 0.f, 0.f, 0.f};

  for (int k0 = kbeg; k0 < kbeg + kpc; k0 += 64) {
#pragma unroll
    for (int j = 0; j < 4; j++) {
      int f = (j << 8) + tid;
      int row = f >> 3, cph = f & 7;
      int clog = cph ^ (row & 7);
      async16(A + (size_t)(m0 + row) * K + k0 + (clog << 3), As + (f << 4));
    }
#pragma unroll
    for (int j = 0; j < 4; j++) {
      int f = (j << 8) + tid;
      int row = f >> 3, cph = f & 7;
      int clog = cph ^ (row & 7);
      async16(Wt + (size_t)(n0 + row) * K + k0 + (clog << 3), Bs + (f << 4));
    }
    __syncthreads();
#pragma unroll
    for (int ks = 0; ks < 2; ks++) {
      const int chunk = (ks << 2) + quad;
      bf16x8 af[4], bfr[4];
#pragma unroll
      for (int mb = 0; mb < 4; mb++) {
        int rw = m_off + (mb << 4) + l16;
        af[mb] = *(const bf16x8*)(As + rw * 128 + ((chunk ^ (rw & 7)) << 4));
      }
#pragma unroll
      for (int nb = 0; nb < 4; nb++) {
        int rw = n_off + (nb << 4) + l16;
        bfr[nb] = *(const bf16x8*)(Bs + rw * 128 + ((chunk ^ (rw & 7)) << 4));
      }
#pragma unroll
      for (int mb = 0; mb < 4; mb++)
#pragma unroll
        for (int nb = 0; nb < 4; nb++)
          acc[mb][nb] = __builtin_amdgcn_mfma_f32_16x16x32_bf16(
              af[mb], bfr[nb], acc[mb][nb], 0, 0, 0);
    }
    __syncthreads();
  }
#pragma unroll
  for (int mb = 0; mb < 4; mb++) {
#pragma unroll
    for (int nb = 0; nb < 4; nb++) {
      int col = n0 + n_off + (nb << 4) + l16;
      float bval = (MODE == 2 && kz != 0) ? 0.f : bias[col];
      if (MODE == 3 && col >= 1024) {
        // fused V transpose with PV key-permutation inside each 32-block:
        int row0 = m0 + m_off + (mb << 4) + (quad << 2);
        int b = row0 / 1280, t = row0 - b * 1280;
        int u0 = t & 31;
        int p0 = ((u0 >> 2) & 3) * 8 + ((u0 & 16) >> 2);
        int tp = (t & ~31) + p0;
        ushx4 pk;
#pragma unroll
        for (int i = 0; i < 4; i++) pk[i] = f2bf(acc[mb][nb][i] + bval);
        *(ushx4*)(vt2 + ((size_t)(b * 512 + col - 1024)) * 1280 + tp) = pk;
      } else {
#pragma unroll
        for (int i = 0; i < 4; i++) {
          int row = m0 + m_off + (mb << 4) + (quad << 2) + i;
          float v = acc[mb][nb][i] + bval;
          if (MODE == 1) v = fmaxf(v, 0.f);
          if (MODE == 0 || MODE == 1) {
            ((ush*)outv)[(size_t)row * N + col] = f2bf(v);
          } else if (MODE == 3) {
            if (col < 512) v *= QSCALE;  // fold softmax scale into Q
            ((ush*)outv)[(size_t)row * 1024 + col] = f2bf(v);
          } else {
            atomicAdd((float*)outv + (size_t)row * N + col, v);
          }
        }
      }
    }
  }
}

// ---------------- attention: LDS-staged K/V, S^T + permuted-key PV ----------
// 2 q-tiles (32 q) per wave sharing the K/V fragment reads.
// qk: (B,T,1024) bf16 [Q(pre-scaled) | K]; vt: (B,512,T) bf16, key-permuted
__global__ __launch_bounds__(256) void k_attn(const ush* __restrict__ qk,
                                              const ush* __restrict__ vt,
                                              ush* __restrict__ y) {
  __shared__ char smem[16384];
  char* Ks = smem;          // 64 keys x 128B, 16B-chunk XOR swizzle
  char* Vs = smem + 8192;   // 64 d-rows x 128B (V^T, key-permuted), same swizzle
  int id = blockIdx.x;
  int xcd = id & 7, slot = id >> 3;
  int bh = xcd * 16 + slot / 10;   // 16 heads per XCD
  int qt = slot % 10;
  int b = bh >> 3, h = bh & 7;
  int tid = threadIdx.x;
  int lane = tid & 63, wave = tid >> 6;
  int quad = lane >> 4, l16 = lane & 15;
  int qbase = qt * 128 + wave * 32;

  // Q as B-operand for two q-tiles: B[k=d=quad*8+j][n=q=l16]
  const ush* qp0 = qk + (size_t)(b * 1280 + qbase + l16) * 1024 + h * 64 + quad * 8;
  const ush* qp1 = qp0 + (size_t)16 * 1024;
  bf16x8 bq0 = *(const bf16x8*)qp0;
  bf16x8 bq1 = *(const bf16x8*)(qp0 + 32);
  bf16x8 bq2 = *(const bf16x8*)qp1;
  bf16x8 bq3 = *(const bf16x8*)(qp1 + 32);

  const ush* kbase = qk + (size_t)(b * 1280) * 1024 + 512 + h * 64;
  const ush* vbase = vt + (size_t)(b * 512 + h * 64) * 1280;

  bf16x8 ones;
#pragma unroll
  for (int e = 0; e < 8; e++) ones[e] = (short)0x3F80;  // bf16 1.0

  fx4 yacc[2][4];
#pragma unroll
  for (int t = 0; t < 2; t++)
#pragma unroll
    for (int nb = 0; nb < 4; nb++) yacc[t][nb] = (fx4){0.f, 0.f, 0.f, 0.f};
  fx4 ysum[2];
  ysum[0] = (fx4){0.f, 0.f, 0.f, 0.f};
  ysum[1] = (fx4){0.f, 0.f, 0.f, 0.f};

  for (int k0 = 0; k0 < 1280; k0 += 64) {
#pragma unroll
    for (int j = 0; j < 2; j++) {
      int f = (j << 8) + tid;
      int key = f >> 3, cph = f & 7, clog = cph ^ (key & 7);
      async16(kbase + (size_t)(k0 + key) * 1024 + (clog << 3), Ks + (f << 4));
    }
#pragma unroll
    for (int j = 0; j < 2; j++) {
      int f = (j << 8) + tid;
      int d = f >> 3, cph = f & 7, clog = cph ^ (d & 7);
      async16(vbase + (size_t)d * 1280 + k0 + (clog << 3), Vs + (f << 4));
    }
    __syncthreads();
#pragma unroll
    for (int g = 0; g < 2; g++) {
      int r0 = g * 32 + l16, r1 = g * 32 + 16 + l16;
      bf16x8 ka0 = *(const bf16x8*)(Ks + r0 * 128 + ((quad ^ (r0 & 7)) << 4));
      bf16x8 ka1 = *(const bf16x8*)(Ks + r0 * 128 + (((4 + quad) ^ (r0 & 7)) << 4));
      bf16x8 kc0 = *(const bf16x8*)(Ks + r1 * 128 + ((quad ^ (r1 & 7)) << 4));
      bf16x8 kc1 = *(const bf16x8*)(Ks + r1 * 128 + (((4 + quad) ^ (r1 & 7)) << 4));
      fx4 s00 = (fx4){0.f, 0.f, 0.f, 0.f}, s10 = (fx4){0.f, 0.f, 0.f, 0.f};
      fx4 s01 = (fx4){0.f, 0.f, 0.f, 0.f}, s11 = (fx4){0.f, 0.f, 0.f, 0.f};
      s00 = __builtin_amdgcn_mfma_f32_16x16x32_bf16(ka0, bq0, s00, 0, 0, 0);
      s00 = __builtin_amdgcn_mfma_f32_16x16x32_bf16(ka1, bq1, s00, 0, 0, 0);
      s10 = __builtin_amdgcn_mfma_f32_16x16x32_bf16(kc0, bq0, s10, 0, 0, 0);
      s10 = __builtin_amdgcn_mfma_f32_16x16x32_bf16(kc1, bq1, s10, 0, 0, 0);
      s01 = __builtin_amdgcn_mfma_f32_16x16x32_bf16(ka0, bq2, s01, 0, 0, 0);
      s01 = __builtin_amdgcn_mfma_f32_16x16x32_bf16(ka1, bq3, s01, 0, 0, 0);
      s11 = __builtin_amdgcn_mfma_f32_16x16x32_bf16(kc0, bq2, s11, 0, 0, 0);
      s11 = __builtin_amdgcn_mfma_f32_16x16x32_bf16(kc1, bq3, s11, 0, 0, 0);
      // p = exp2(s) (scale pre-folded into Q); pack pairs with cvt_pk_bf16
      bf16x8 pf0, pf1;
      {
        float p0 = fast_exp2(s00[0]), p1 = fast_exp2(s00[1]);
        float p2 = fast_exp2(s00[2]), p3 = fast_exp2(s00[3]);
        float p4 = fast_exp2(s10[0]), p5 = fast_exp2(s10[1]);
        float p6 = fast_exp2(s10[2]), p7 = fast_exp2(s10[3]);
        int4 pi = make_int4((int)pk_bf16(p0, p1), (int)pk_bf16(p2, p3),
                            (int)pk_bf16(p4, p5), (int)pk_bf16(p6, p7));
        pf0 = *(bf16x8*)&pi;
      }
      {
        float p0 = fast_exp2(s01[0]), p1 = fast_exp2(s01[1]);
        float p2 = fast_exp2(s01[2]), p3 = fast_exp2(s01[3]);
        float p4 = fast_exp2(s11[0]), p5 = fast_exp2(s11[1]);
        float p6 = fast_exp2(s11[2]), p7 = fast_exp2(s11[3]);
        int4 pi = make_int4((int)pk_bf16(p0, p1), (int)pk_bf16(p2, p3),
                            (int)pk_bf16(p4, p5), (int)pk_bf16(p6, p7));
        pf1 = *(bf16x8*)&pi;
      }
      // row-sums via ones-MFMA
      ysum[0] = __builtin_amdgcn_mfma_f32_16x16x32_bf16(pf0, ones, ysum[0], 0, 0, 0);
      ysum[1] = __builtin_amdgcn_mfma_f32_16x16x32_bf16(pf1, ones, ysum[1], 0, 0, 0);
      // PV: V fragments shared by both q-tiles
#pragma unroll
      for (int nb = 0; nb < 4; nb++) {
        int d = nb * 16 + l16;
        bf16x8 vf = *(const bf16x8*)(Vs + d * 128 +
                                     (((g * 4 + quad) ^ (d & 7)) << 4));
        yacc[0][nb] = __builtin_amdgcn_mfma_f32_16x16x32_bf16(pf0, vf, yacc[0][nb], 0, 0, 0);
        yacc[1][nb] = __builtin_amdgcn_mfma_f32_16x16x32_bf16(pf1, vf, yacc[1][nb], 0, 0, 0);
      }
    }
    __syncthreads();
  }
#pragma unroll
  for (int t = 0; t < 2; t++) {
    float rl[4];
#pragma unroll
    for (int i = 0; i < 4; i++) rl[i] = 1.0f / ysum[t][i];
#pragma unroll
    for (int nb = 0; nb < 4; nb++)
#pragma unroll
      for (int i = 0; i < 4; i++) {
        int tr = qbase + t * 16 + quad * 4 + i;
        int col = h * 64 + nb * 16 + l16;
        y[(size_t)(b * 1280 + tr) * 512 + col] = f2bf(yacc[t][nb][i] * rl[i]);
      }
  }
}

// ---------------- host ------------------------------------------------------
extern "C" void kernel_launch(void* const* d_in, const int* in_sizes, int n_in,
                              void* d_out, int out_size, void* d_ws, size_t ws_size,
                              hipStream_t stream) {
  const float* img = (const float*)d_in[0];
  const float* rad = (const float*)d_in[1];
  const float* pos = (const float*)d_in[2];
  const float* ln1w = (const float*)d_in[3];
  const float* ln1b = (const float*)d_in[4];
  const float* Wq = (const float*)d_in[5];
  const float* bq = (const float*)d_in[6];
  const float* Wk = (const float*)d_in[7];
  const float* bk = (const float*)d_in[8];
  const float* Wv = (const float*)d_in[9];
  const float* bv = (const float*)d_in[10];
  const float* Wo = (const float*)d_in[11];
  const float* bo = (const float*)d_in[12];
  const float* ln2w = (const float*)d_in[13];
  const float* ln2b = (const float*)d_in[14];
  const float* W1 = (const float*)d_in[15];
  const float* b1 = (const float*)d_in[16];
  const float* W2 = (const float*)d_in[17];
  const float* b2 = (const float*)d_in[18];
  const float* lnfw = (const float*)d_in[19];
  const float* lnfb = (const float*)d_in[20];

  char* ws = (char*)d_ws;
  float* xw = (float*)(ws + 0);                  // 41,943,040 B fp32 x
  ush* h    = (ush*)(ws + 41943040);             // 20,971,520 B bf16 h
  ush* qk   = (ush*)(ws + 62914560);             // 41,943,040 B bf16 [Q|K] (M,1024)
  ush* vt   = (ush*)(ws + 104857600);            // 20,971,520 B bf16 V^T (B,512,T)
  ush* y    = (ush*)(ws + 125829120);            // 20,971,520 B bf16 y
  ush* u    = (ush*)(ws + 62914560);             // 83,886,080 B bf16 u (overlays qk/vt/y)
  ush* wbf  = (ush*)(ws + 146800640);            // 37,748,736 B bf16 weights^T
  float* qkvb = (float*)(ws + 184549376);        // 36,864 B packed qkv bias

  k_prep_weights<<<18432, 256, 0, stream>>>(Wq, Wk, Wv, Wo, W1, W2, wbf);
  k_pack_bias<<<36, 256, 0, stream>>>(bq, bk, bv, qkvb);
  k_embed<<<10240, 256, 0, stream>>>(img, rad, pos, xw);

  for (int l = 0; l < 6; l++) {
    const ush* wl = wbf + (size_t)l * WSTRIDE;
    k_ln_bf16<<<5120, 256, 0, stream>>>(xw, ln1w + l * 512, ln1b + l * 512, h);
    k_gemm<3><<<dim3(12, 160), 256, 0, stream>>>(h, wl, qkvb + l * 1536, qk, vt, 20480, 1536, 512, 1);
    k_attn<<<1280, 256, 0, stream>>>(qk, vt, y);
    k_gemm<2><<<dim3(4, 320), 256, 0, stream>>>(y, wl + 786432, bo + l * 512, xw, nullptr, 20480, 512, 512, 2);
    k_ln_bf16<<<5120, 256, 0, stream>>>(xw, ln2w + l * 512, ln2b + l * 512, h);
    k_gemm<1><<<dim3(16, 160), 256, 0, stream>>>(h, wl + 1048576, b1 + l * 2048, u, nullptr, 20480, 2048, 512, 1);
    k_gemm<2><<<dim3(4, 320), 256, 0, stream>>>(u, wl + 2097152, b2 + l * 512, xw, nullptr, 20480, 512, 2048, 2);
  }
  k_ln_final<<<5120, 256, 0, stream>>>(xw, lnfw, lnfb, (float*)d_out);
}

// Round 9
// 1916.939 us; speedup vs baseline: 1.2545x; 1.2545x over previous
//
#include <hip/hip_runtime.h>
#include <stdint.h>

typedef __attribute__((ext_vector_type(8))) short bf16x8;
typedef __attribute__((ext_vector_type(4))) short bf16x4;
typedef __attribute__((ext_vector_type(4))) float fx4;
typedef __attribute__((ext_vector_type(4))) unsigned short ushx4;
typedef unsigned short ush;

#define DEV __device__ __forceinline__

DEV unsigned short f2bf(float f) {
  unsigned u = __float_as_uint(f);
  u += 0x7fffu + ((u >> 16) & 1u);
  return (unsigned short)(u >> 16);
}

DEV float bf2f(ush u) { return __uint_as_float(((unsigned)u) << 16); }

DEV float fast_exp2(float x) { return __builtin_amdgcn_exp2f(x); }

// packed f32x2 -> bf16x2 (RNE), single VALU op
DEV unsigned pk_bf16(float a, float b) {
  unsigned r;
  asm("v_cvt_pk_bf16_f32 %0, %1, %2" : "=v"(r) : "v"(a), "v"(b));
  return r;
}

DEV void async16(const void* g, void* l) {
  __builtin_amdgcn_global_load_lds(
      (const __attribute__((address_space(1))) unsigned*)g,
      (__attribute__((address_space(3))) unsigned*)l, 16, 0, 0);
}

// softmax scale folded into Q: 1/sqrt(64) * log2(e)
#define QSCALE 0.18033688011112042f

// ---------------- weight prep: fp32 (K,N) -> bf16 (N,K) transposed ----------
#define WSTRIDE 3145728

__global__ __launch_bounds__(256) void k_prep_weights(
    const float* __restrict__ Wq, const float* __restrict__ Wk,
    const float* __restrict__ Wv, const float* __restrict__ Wo,
    const float* __restrict__ W1, const float* __restrict__ W2,
    ush* __restrict__ wbf) {
  __shared__ float tile[32][33];
  int bid = blockIdx.x;
  int l = bid / 3072, r = bid % 3072;
  const float* src; ush* dst; int R, Cc, t;
  if (r < 768) {
    int w = r >> 8; t = r & 255; R = 512; Cc = 512;
    src = (w == 0 ? Wq : (w == 1 ? Wk : Wv)) + (size_t)l * 262144;
    dst = wbf + (size_t)l * WSTRIDE + w * 262144;
  } else if (r < 1024) {
    t = r - 768; R = 512; Cc = 512;
    src = Wo + (size_t)l * 262144; dst = wbf + (size_t)l * WSTRIDE + 786432;
  } else if (r < 2048) {
    t = r - 1024; R = 512; Cc = 2048;
    src = W1 + (size_t)l * 1048576; dst = wbf + (size_t)l * WSTRIDE + 1048576;
  } else {
    t = r - 2048; R = 2048; Cc = 512;
    src = W2 + (size_t)l * 1048576; dst = wbf + (size_t)l * WSTRIDE + 2097152;
  }
  int tpr = Cc >> 5;
  int trow = t / tpr, tcol = t % tpr;
  int tx = threadIdx.x & 31, ty = threadIdx.x >> 5;
#pragma unroll
  for (int i = 0; i < 4; i++) {
    int rr = trow * 32 + ty + i * 8, cc = tcol * 32 + tx;
    tile[ty + i * 8][tx] = src[(size_t)rr * Cc + cc];
  }
  __syncthreads();
#pragma unroll
  for (int i = 0; i < 4; i++) {
    int cc = tcol * 32 + ty + i * 8, rr = trow * 32 + tx;
    dst[(size_t)cc * R + rr] = f2bf(tile[tx][ty + i * 8]);
  }
}

__global__ __launch_bounds__(256) void k_pack_bias(
    const float* __restrict__ bq, const float* __restrict__ bk,
    const float* __restrict__ bv, float* __restrict__ dst) {
  int idx = blockIdx.x * 256 + threadIdx.x;
  if (idx >= 6 * 1536) return;
  int l = idx / 1536, r = idx % 1536;
  float v = (r < 512) ? bq[l * 512 + r]
            : (r < 1024) ? bk[l * 512 + r - 512] : bv[l * 512 + r - 1024];
  dst[idx] = v;
}

// ---------------- embed: (B,C,HW) transpose -> x (B,T,C) fp32 + pos ---------
__global__ __launch_bounds__(256) void k_embed(
    const float* __restrict__ img, const float* __restrict__ rad,
    const float* __restrict__ pos, float* __restrict__ x) {
  __shared__ float tile[32][33];
  int bid = blockIdx.x;
  int b = bid / 640, r2 = bid % 640;
  int tc = r2 / 40, tt = r2 % 40;
  int tx = threadIdx.x & 31, ty = threadIdx.x >> 5;
#pragma unroll
  for (int i = 0; i < 4; i++) {
    int c = tc * 32 + ty + i * 8, t = tt * 32 + tx;
    float v = (t < 1024) ? img[(size_t)(b * 512 + c) * 1024 + t]
                         : rad[(size_t)(b * 512 + c) * 256 + (t - 1024)];
    tile[ty + i * 8][tx] = v;
  }
  __syncthreads();
#pragma unroll
  for (int i = 0; i < 4; i++) {
    int t = tt * 32 + ty + i * 8, c = tc * 32 + tx;
    x[(size_t)(b * 1280 + t) * 512 + c] = tile[tx][ty + i * 8] + pos[(size_t)t * 512 + c];
  }
}

// ---------------- layernorm (fp32 in, bf16 out): one wave per row -----------
__global__ __launch_bounds__(256) void k_ln_bf16(
    const float* __restrict__ x, const float* __restrict__ w,
    const float* __restrict__ bia, ush* __restrict__ h) {
  int wave = threadIdx.x >> 6, lane = threadIdx.x & 63;
  int row = blockIdx.x * 4 + wave;
  int c0 = lane * 8;
  const float4* xr = (const float4*)(x + (size_t)row * 512 + c0);
  float4 a = xr[0], b4 = xr[1];
  float v[8] = {a.x, a.y, a.z, a.w, b4.x, b4.y, b4.z, b4.w};
  float s = 0.f, s2 = 0.f;
#pragma unroll
  for (int e = 0; e < 8; e++) { s += v[e]; s2 += v[e] * v[e]; }
#pragma unroll
  for (int mask = 1; mask < 64; mask <<= 1) {
    s += __shfl_xor(s, mask, 64);
    s2 += __shfl_xor(s2, mask, 64);
  }
  float mean = s * (1.f / 512.f);
  float var = s2 * (1.f / 512.f) - mean * mean;
  float rstd = rsqrtf(var + 1e-5f);
  bf16x8 o;
#pragma unroll
  for (int e = 0; e < 8; e++)
    o[e] = (short)f2bf((v[e] - mean) * rstd * w[c0 + e] + bia[c0 + e]);
  *(bf16x8*)(h + (size_t)row * 512 + c0) = o;
}

__global__ __launch_bounds__(256) void k_ln_final(
    const float* __restrict__ x, const float* __restrict__ w,
    const float* __restrict__ bia, float* __restrict__ out) {
  int wave = threadIdx.x >> 6, lane = threadIdx.x & 63;
  int row = blockIdx.x * 4 + wave;
  int c0 = lane * 8;
  const float4* xr = (const float4*)(x + (size_t)row * 512 + c0);
  float4 a = xr[0], b4 = xr[1];
  float v[8] = {a.x, a.y, a.z, a.w, b4.x, b4.y, b4.z, b4.w};
  float s = 0.f, s2 = 0.f;
#pragma unroll
  for (int e = 0; e < 8; e++) { s += v[e]; s2 += v[e] * v[e]; }
#pragma unroll
  for (int mask = 1; mask < 64; mask <<= 1) {
    s += __shfl_xor(s, mask, 64);
    s2 += __shfl_xor(s2, mask, 64);
  }
  float mean = s * (1.f / 512.f);
  float var = s2 * (1.f / 512.f) - mean * mean;
  float rstd = rsqrtf(var + 1e-5f);
  int b = row / 1280, t = row % 1280;
  size_t orow = (t < 1024) ? ((size_t)b * 1024 + t)
                           : (16384 + (size_t)b * 256 + (t - 1024));
  float o[8];
#pragma unroll
  for (int e = 0; e < 8; e++)
    o[e] = (v[e] - mean) * rstd * w[c0 + e] + bia[c0 + e];
  float4* op = (float4*)(out + orow * 512 + c0);
  op[0] = make_float4(o[0], o[1], o[2], o[3]);
  op[1] = make_float4(o[4], o[5], o[6], o[7]);
}

// ---------------- GEMM: A (M,K) bf16 row-major @ Wt (N,K) bf16 row-major ----
// Tile MT x 128 (MT=128 or 64). XCD-swizzled grid: n-blocks of an m-strip on
// one XCD so the A-strip is fetched into that XCD's L2 once.
// MODE 0: out bf16; MODE 1: bf16+ReLU; MODE 2: fp32 residual +=;
// MODE 3: QKV — col<512: Q pre-scaled; 512..1023: K; >=1024: V -> vt permuted
template <int MODE, int MT>
__global__ __launch_bounds__(256) void k_gemm(
    const ush* __restrict__ A, const ush* __restrict__ Wt,
    const float* __restrict__ bias, void* __restrict__ outv,
    ush* __restrict__ vt2, int M, int N, int K) {
  constexpr int MB = MT / 32;          // m-frags per wave
  __shared__ char smem[MT * 128 + 16384];
  char* As = smem;
  char* Bs = smem + MT * 128;
  const int tid = threadIdx.x;
  // XCD swizzle: id = y*gx+x; xcd = id&7; per-XCD: n-blocks contiguous
  int id = blockIdx.y * gridDim.x + blockIdx.x;
  int xcd = id & 7, s = id >> 3;
  int nb_n = gridDim.x;
  int strips_per_xcd = gridDim.y >> 3;
  int mblk = xcd * strips_per_xcd + s / nb_n;
  int nblk = s % nb_n;
  const int m0 = mblk * MT, n0 = nblk << 7;
  const int lane = tid & 63, wave = tid >> 6;
  const int quad = lane >> 4, l16 = lane & 15;
  const int m_off = (wave & 1) * (MT / 2), n_off = (wave >> 1) << 6;
  fx4 acc[MB][4];
#pragma unroll
  for (int a = 0; a < MB; a++)
#pragma unroll
    for (int b = 0; b < 4; b++) acc[a][b] = (fx4){0.f, 0.f, 0.f, 0.f};

  for (int k0 = 0; k0 < K; k0 += 64) {
#pragma unroll
    for (int j = 0; j < MT / 32; j++) {
      int f = (j << 8) + tid;
      int row = f >> 3, cph = f & 7;
      int clog = cph ^ (row & 7);
      async16(A + (size_t)(m0 + row) * K + k0 + (clog << 3), As + (f << 4));
    }
#pragma unroll
    for (int j = 0; j < 4; j++) {
      int f = (j << 8) + tid;
      int row = f >> 3, cph = f & 7;
      int clog = cph ^ (row & 7);
      async16(Wt + (size_t)(n0 + row) * K + k0 + (clog << 3), Bs + (f << 4));
    }
    __syncthreads();
#pragma unroll
    for (int ks = 0; ks < 2; ks++) {
      const int chunk = (ks << 2) + quad;
      bf16x8 af[MB], bfr[4];
#pragma unroll
      for (int mb = 0; mb < MB; mb++) {
        int rw = m_off + (mb << 4) + l16;
        af[mb] = *(const bf16x8*)(As + rw * 128 + ((chunk ^ (rw & 7)) << 4));
      }
#pragma unroll
      for (int nb = 0; nb < 4; nb++) {
        int rw = n_off + (nb << 4) + l16;
        bfr[nb] = *(const bf16x8*)(Bs + rw * 128 + ((chunk ^ (rw & 7)) << 4));
      }
#pragma unroll
      for (int mb = 0; mb < MB; mb++)
#pragma unroll
        for (int nb = 0; nb < 4; nb++)
          acc[mb][nb] = __builtin_amdgcn_mfma_f32_16x16x32_bf16(
              af[mb], bfr[nb], acc[mb][nb], 0, 0, 0);
    }
    __syncthreads();
  }
#pragma unroll
  for (int mb = 0; mb < MB; mb++) {
#pragma unroll
    for (int nb = 0; nb < 4; nb++) {
      int col = n0 + n_off + (nb << 4) + l16;
      float bval = bias[col];
      if (MODE == 3 && col >= 1024) {
        // fused V transpose with PV key-permutation inside each 32-block:
        int row0 = m0 + m_off + (mb << 4) + (quad << 2);
        int b = row0 / 1280, t = row0 - b * 1280;
        int u0 = t & 31;
        int p0 = ((u0 >> 2) & 3) * 8 + ((u0 & 16) >> 2);
        int tp = (t & ~31) + p0;
        ushx4 pk;
#pragma unroll
        for (int i = 0; i < 4; i++) pk[i] = f2bf(acc[mb][nb][i] + bval);
        *(ushx4*)(vt2 + ((size_t)(b * 512 + col - 1024)) * 1280 + tp) = pk;
      } else {
#pragma unroll
        for (int i = 0; i < 4; i++) {
          int row = m0 + m_off + (mb << 4) + (quad << 2) + i;
          float v = acc[mb][nb][i] + bval;
          if (MODE == 1) v = fmaxf(v, 0.f);
          if (MODE == 0 || MODE == 1) {
            ((ush*)outv)[(size_t)row * N + col] = f2bf(v);
          } else if (MODE == 3) {
            if (col < 512) v *= QSCALE;  // fold softmax scale into Q
            ((ush*)outv)[(size_t)row * 1024 + col] = f2bf(v);
          } else {
            float* X = (float*)outv;
            X[(size_t)row * N + col] += v;
          }
        }
      }
    }
  }
}

// ---------------- attention: LDS-staged K/V, S^T + permuted-key PV ----------
// 2 q-tiles (32 q) per wave sharing the K/V fragment reads.
// qk: (B,T,1024) bf16 [Q(pre-scaled) | K]; vt: (B,512,T) bf16, key-permuted
__global__ __launch_bounds__(256) void k_attn(const ush* __restrict__ qk,
                                              const ush* __restrict__ vt,
                                              ush* __restrict__ y) {
  __shared__ char smem[16384];
  char* Ks = smem;          // 64 keys x 128B, 16B-chunk XOR swizzle
  char* Vs = smem + 8192;   // 64 d-rows x 128B (V^T, key-permuted), same swizzle
  int id = blockIdx.x;
  int xcd = id & 7, slot = id >> 3;
  int bh = xcd * 16 + slot / 10;   // 16 heads per XCD
  int qt = slot % 10;
  int b = bh >> 3, h = bh & 7;
  int tid = threadIdx.x;
  int lane = tid & 63, wave = tid >> 6;
  int quad = lane >> 4, l16 = lane & 15;
  int qbase = qt * 128 + wave * 32;

  // Q as B-operand for two q-tiles: B[k=d=quad*8+j][n=q=l16]
  const ush* qp0 = qk + (size_t)(b * 1280 + qbase + l16) * 1024 + h * 64 + quad * 8;
  const ush* qp1 = qp0 + (size_t)16 * 1024;
  bf16x8 bq0 = *(const bf16x8*)qp0;
  bf16x8 bq1 = *(const bf16x8*)(qp0 + 32);
  bf16x8 bq2 = *(const bf16x8*)qp1;
  bf16x8 bq3 = *(const bf16x8*)(qp1 + 32);

  const ush* kbase = qk + (size_t)(b * 1280) * 1024 + 512 + h * 64;
  const ush* vbase = vt + (size_t)(b * 512 + h * 64) * 1280;

  bf16x8 ones;
#pragma unroll
  for (int e = 0; e < 8; e++) ones[e] = (short)0x3F80;  // bf16 1.0

  fx4 yacc[2][4];
#pragma unroll
  for (int t = 0; t < 2; t++)
#pragma unroll
    for (int nb = 0; nb < 4; nb++) yacc[t][nb] = (fx4){0.f, 0.f, 0.f, 0.f};
  fx4 ysum[2];
  ysum[0] = (fx4){0.f, 0.f, 0.f, 0.f};
  ysum[1] = (fx4){0.f, 0.f, 0.f, 0.f};

  for (int k0 = 0; k0 < 1280; k0 += 64) {
#pragma unroll
    for (int j = 0; j < 2; j++) {
      int f = (j << 8) + tid;
      int key = f >> 3, cph = f & 7, clog = cph ^ (key & 7);
      async16(kbase + (size_t)(k0 + key) * 1024 + (clog << 3), Ks + (f << 4));
    }
#pragma unroll
    for (int j = 0; j < 2; j++) {
      int f = (j << 8) + tid;
      int d = f >> 3, cph = f & 7, clog = cph ^ (d & 7);
      async16(vbase + (size_t)d * 1280 + k0 + (clog << 3), Vs + (f << 4));
    }
    __syncthreads();
#pragma unroll
    for (int g = 0; g < 2; g++) {
      int r0 = g * 32 + l16, r1 = g * 32 + 16 + l16;
      bf16x8 ka0 = *(const bf16x8*)(Ks + r0 * 128 + ((quad ^ (r0 & 7)) << 4));
      bf16x8 ka1 = *(const bf16x8*)(Ks + r0 * 128 + (((4 + quad) ^ (r0 & 7)) << 4));
      bf16x8 kc0 = *(const bf16x8*)(Ks + r1 * 128 + ((quad ^ (r1 & 7)) << 4));
      bf16x8 kc1 = *(const bf16x8*)(Ks + r1 * 128 + (((4 + quad) ^ (r1 & 7)) << 4));
      fx4 s00 = (fx4){0.f, 0.f, 0.f, 0.f}, s10 = (fx4){0.f, 0.f, 0.f, 0.f};
      fx4 s01 = (fx4){0.f, 0.f, 0.f, 0.f}, s11 = (fx4){0.f, 0.f, 0.f, 0.f};
      s00 = __builtin_amdgcn_mfma_f32_16x16x32_bf16(ka0, bq0, s00, 0, 0, 0);
      s00 = __builtin_amdgcn_mfma_f32_16x16x32_bf16(ka1, bq1, s00, 0, 0, 0);
      s10 = __builtin_amdgcn_mfma_f32_16x16x32_bf16(kc0, bq0, s10, 0, 0, 0);
      s10 = __builtin_amdgcn_mfma_f32_16x16x32_bf16(kc1, bq1, s10, 0, 0, 0);
      s01 = __builtin_amdgcn_mfma_f32_16x16x32_bf16(ka0, bq2, s01, 0, 0, 0);
      s01 = __builtin_amdgcn_mfma_f32_16x16x32_bf16(ka1, bq3, s01, 0, 0, 0);
      s11 = __builtin_amdgcn_mfma_f32_16x16x32_bf16(kc0, bq2, s11, 0, 0, 0);
      s11 = __builtin_amdgcn_mfma_f32_16x16x32_bf16(kc1, bq3, s11, 0, 0, 0);
      // p = exp2(s) (scale pre-folded into Q); pack pairs with cvt_pk_bf16
      bf16x8 pf0, pf1;
      {
        float p0 = fast_exp2(s00[0]), p1 = fast_exp2(s00[1]);
        float p2 = fast_exp2(s00[2]), p3 = fast_exp2(s00[3]);
        float p4 = fast_exp2(s10[0]), p5 = fast_exp2(s10[1]);
        float p6 = fast_exp2(s10[2]), p7 = fast_exp2(s10[3]);
        int4 pi = make_int4((int)pk_bf16(p0, p1), (int)pk_bf16(p2, p3),
                            (int)pk_bf16(p4, p5), (int)pk_bf16(p6, p7));
        pf0 = *(bf16x8*)&pi;
      }
      {
        float p0 = fast_exp2(s01[0]), p1 = fast_exp2(s01[1]);
        float p2 = fast_exp2(s01[2]), p3 = fast_exp2(s01[3]);
        float p4 = fast_exp2(s11[0]), p5 = fast_exp2(s11[1]);
        float p6 = fast_exp2(s11[2]), p7 = fast_exp2(s11[3]);
        int4 pi = make_int4((int)pk_bf16(p0, p1), (int)pk_bf16(p2, p3),
                            (int)pk_bf16(p4, p5), (int)pk_bf16(p6, p7));
        pf1 = *(bf16x8*)&pi;
      }
      // row-sums via ones-MFMA
      ysum[0] = __builtin_amdgcn_mfma_f32_16x16x32_bf16(pf0, ones, ysum[0], 0, 0, 0);
      ysum[1] = __builtin_amdgcn_mfma_f32_16x16x32_bf16(pf1, ones, ysum[1], 0, 0, 0);
      // PV: V fragments shared by both q-tiles
#pragma unroll
      for (int nb = 0; nb < 4; nb++) {
        int d = nb * 16 + l16;
        bf16x8 vf = *(const bf16x8*)(Vs + d * 128 +
                                     (((g * 4 + quad) ^ (d & 7)) << 4));
        yacc[0][nb] = __builtin_amdgcn_mfma_f32_16x16x32_bf16(pf0, vf, yacc[0][nb], 0, 0, 0);
        yacc[1][nb] = __builtin_amdgcn_mfma_f32_16x16x32_bf16(pf1, vf, yacc[1][nb], 0, 0, 0);
      }
    }
    __syncthreads();
  }
#pragma unroll
  for (int t = 0; t < 2; t++) {
    float rl[4];
#pragma unroll
    for (int i = 0; i < 4; i++) rl[i] = 1.0f / ysum[t][i];
#pragma unroll
    for (int nb = 0; nb < 4; nb++)
#pragma unroll
      for (int i = 0; i < 4; i++) {
        int tr = qbase + t * 16 + quad * 4 + i;
        int col = h * 64 + nb * 16 + l16;
        y[(size_t)(b * 1280 + tr) * 512 + col] = f2bf(yacc[t][nb][i] * rl[i]);
      }
  }
}

// ---------------- host ------------------------------------------------------
extern "C" void kernel_launch(void* const* d_in, const int* in_sizes, int n_in,
                              void* d_out, int out_size, void* d_ws, size_t ws_size,
                              hipStream_t stream) {
  const float* img = (const float*)d_in[0];
  const float* rad = (const float*)d_in[1];
  const float* pos = (const float*)d_in[2];
  const float* ln1w = (const float*)d_in[3];
  const float* ln1b = (const float*)d_in[4];
  const float* Wq = (const float*)d_in[5];
  const float* bq = (const float*)d_in[6];
  const float* Wk = (const float*)d_in[7];
  const float* bk = (const float*)d_in[8];
  const float* Wv = (const float*)d_in[9];
  const float* bv = (const float*)d_in[10];
  const float* Wo = (const float*)d_in[11];
  const float* bo = (const float*)d_in[12];
  const float* ln2w = (const float*)d_in[13];
  const float* ln2b = (const float*)d_in[14];
  const float* W1 = (const float*)d_in[15];
  const float* b1 = (const float*)d_in[16];
  const float* W2 = (const float*)d_in[17];
  const float* b2 = (const float*)d_in[18];
  const float* lnfw = (const float*)d_in[19];
  const float* lnfb = (const float*)d_in[20];

  char* ws = (char*)d_ws;
  float* xw = (float*)(ws + 0);                  // 41,943,040 B fp32 x
  ush* h    = (ush*)(ws + 41943040);             // 20,971,520 B bf16 h
  ush* qk   = (ush*)(ws + 62914560);             // 41,943,040 B bf16 [Q|K] (M,1024)
  ush* vt   = (ush*)(ws + 104857600);            // 20,971,520 B bf16 V^T (B,512,T)
  ush* y    = (ush*)(ws + 125829120);            // 20,971,520 B bf16 y
  ush* u    = (ush*)(ws + 62914560);             // 83,886,080 B bf16 u (overlays qk/vt/y)
  ush* wbf  = (ush*)(ws + 146800640);            // 37,748,736 B bf16 weights^T
  float* qkvb = (float*)(ws + 184549376);        // 36,864 B packed qkv bias

  k_prep_weights<<<18432, 256, 0, stream>>>(Wq, Wk, Wv, Wo, W1, W2, wbf);
  k_pack_bias<<<36, 256, 0, stream>>>(bq, bk, bv, qkvb);
  k_embed<<<10240, 256, 0, stream>>>(img, rad, pos, xw);

  for (int l = 0; l < 6; l++) {
    const ush* wl = wbf + (size_t)l * WSTRIDE;
    k_ln_bf16<<<5120, 256, 0, stream>>>(xw, ln1w + l * 512, ln1b + l * 512, h);
    k_gemm<3, 128><<<dim3(12, 160), 256, 0, stream>>>(h, wl, qkvb + l * 1536, qk, vt, 20480, 1536, 512);
    k_attn<<<1280, 256, 0, stream>>>(qk, vt, y);
    k_gemm<2, 64><<<dim3(4, 320), 256, 0, stream>>>(y, wl + 786432, bo + l * 512, xw, nullptr, 20480, 512, 512);
    k_ln_bf16<<<5120, 256, 0, stream>>>(xw, ln2w + l * 512, ln2b + l * 512, h);
    k_gemm<1, 128><<<dim3(16, 160), 256, 0, stream>>>(h, wl + 1048576, b1 + l * 2048, u, nullptr, 20480, 2048, 512);
    k_gemm<2, 64><<<dim3(4, 320), 256, 0, stream>>>(u, wl + 2097152, b2 + l * 512, xw, nullptr, 20480, 512, 2048);
  }
  k_ln_final<<<5120, 256, 0, stream>>>(xw, lnfw, lnfb, (float*)d_out);
}